// Round 5
// baseline (726.442 us; speedup 1.0000x reference)
//
#include <hip/hip_runtime.h>
#include <math.h>

#define NB 4
#define NF 64
#define NPIX 16384
#define DK 256
#define DV 512
#define QKSCALE 0.4204482f

typedef __attribute__((ext_vector_type(8))) short bf16x8;
typedef __attribute__((ext_vector_type(4))) float f32x4;
#define MFMA16(a, b, c) __builtin_amdgcn_mfma_f32_16x16x32_bf16(a, b, c, 0, 0, 0)

__device__ __forceinline__ short f2bf(float f) {
  unsigned u = __builtin_bit_cast(unsigned, f);
  unsigned r = (u + 0x7FFFu + ((u >> 16) & 1u)) >> 16;
  return (short)r;
}
__device__ __forceinline__ float bf2f(short s) {
  unsigned u = ((unsigned)(unsigned short)s) << 16;
  return __builtin_bit_cast(float, u);
}

// workspace offsets (float units)
#define OFF_XUPT   0L          // bf16 [4][128y][128x][128c]  4,194,304 f
#define OFF_XAT    4194304L    // bf16 [4][128y][128x][64c]   2,097,152 f
#define OFF_GPART  6291456L    // bf16 [4][128][256][80]      5,242,880 f
#define OFF_WB1    11534336L   // bf16 [9][64][128]              36,864 f
#define OFF_WB2    11571200L   // bf16 [9][64][64]               18,432 f
#define OFF_STYLE  11589632L   // [4][64] fp32                      256
#define OFF_RGBS   11589888L   // [4][3][128][128] fp32         196,608
#define OFF_QWB    11786496L   // bf16 [2][256][64]              16,384 f
#define OFF_KWB    11802880L   // bf16 [2][256][64]              16,384 f
#define OFF_F1WB   11819264L   // bf16 [2][128][64]               8,192 f
#define OFF_F2WB   11827456L   // bf16 [2][64][128]               8,192 f
#define OFF_MTT    11835648L   // bf16 [4][64][256]              32,768 f
// total 11,868,416 floats = 47.5 MB

#define CDIV(a,b) (((a)+(b)-1)/(b))

// ---------------- fp32->bf16 for the 4 attn weight tensors in one launch -----------------
__global__ void cvt4_kernel(const float* __restrict__ qw, const float* __restrict__ kw,
                            const float* __restrict__ f1w, const float* __restrict__ f2w,
                            short* __restrict__ qwb, short* __restrict__ kwb,
                            short* __restrict__ f1wb, short* __restrict__ f2wb) {
  int i = blockIdx.x * 256 + threadIdx.x;   // 98304 total
  if (i < 32768) qwb[i] = f2bf(qw[i]);
  else if (i < 65536) kwb[i - 32768] = f2bf(kw[i - 32768]);
  else if (i < 81920) f1wb[i - 65536] = f2bf(f1w[i - 65536]);
  else f2wb[i - 81920] = f2bf(f2w[i - 81920]);
}

// ---------------- fused bilinear up2 + NCHW->NHWC bf16 (x path) --------------------------
// grid (128 y_out, NB). in: [4][128][64][64] fp32. out: xupT bf16 [b][y][x][128c]
__global__ __launch_bounds__(256) void up2t_kernel(const float* __restrict__ in,
                                                   short* __restrict__ outT) {
  __shared__ float row[64 * 132];   // [xin][c] y-interpolated row
  int b = blockIdx.y, y = blockIdx.x, tid = threadIdx.x;
  float iy = y * 0.5f - 0.25f;
  int y0 = (int)floorf(iy); float wy = iy - (float)y0;
  int ylo = y0 < 0 ? 0 : y0;
  int yhi = y0 + 1 > 63 ? 63 : y0 + 1;
  for (int it = 0; it < 32; ++it) {
    int idx = it * 256 + tid;
    int c = idx >> 6, xin = idx & 63;
    const float* bp = in + ((long)(b * 128 + c)) * 4096;
    float v0 = bp[ylo * 64 + xin];
    float v1 = bp[yhi * 64 + xin];
    row[xin * 132 + c] = (1.f - wy) * v0 + wy * v1;
  }
  __syncthreads();
  int x = tid >> 1, c0 = (tid & 1) * 64;
  float ix = x * 0.5f - 0.25f;
  int x0 = (int)floorf(ix); float wx = ix - (float)x0;
  int xlo = x0 < 0 ? 0 : x0;
  int xhi = x0 + 1 > 63 ? 63 : x0 + 1;
  long obase = (((long)(b * 128 + y)) * 128 + x) * 128 + c0;
#pragma unroll
  for (int i = 0; i < 8; ++i) {
    bf16x8 pack;
#pragma unroll
    for (int r = 0; r < 8; ++r) {
      int c = c0 + i * 8 + r;
      float v = (1.f - wx) * row[xlo * 132 + c] + wx * row[xhi * 132 + c];
      pack[r] = f2bf(v);
    }
    *(bf16x8*)(outT + obase + i * 8) = pack;
  }
}

// ---------------- demod weight prep -> bf16 wb[9][64][CI] --------------------------------
__global__ void wnormT_kernel(const float* __restrict__ W, short* __restrict__ wb, int CI) {
  int co = blockIdx.x;
  int n = CI * 9;
  __shared__ float red[256];
  float s = 0.f;
  for (int idx = threadIdx.x; idx < n; idx += 256) {
    float w2 = 2.0f * W[co * n + idx];
    s += w2 * w2;
  }
  red[threadIdx.x] = s;
  __syncthreads();
  for (int off = 128; off > 0; off >>= 1) {
    if (threadIdx.x < off) red[threadIdx.x] += red[threadIdx.x + off];
    __syncthreads();
  }
  float sc = rsqrtf(red[0] + 1e-8f);
  for (int idx = threadIdx.x; idx < n; idx += 256) {
    int ci = idx / 9, k = idx - ci * 9;
    wb[(k * 64 + co) * CI + ci] = f2bf(2.0f * W[co * n + idx] * sc);
  }
}

// ---------------- style ------------------------------------------------------------------
__global__ void style_kernel(const float* __restrict__ istyle, const float* __restrict__ sw,
                             const float* __restrict__ sb, float* __restrict__ styleb) {
  int b = threadIdx.x >> 6;
  int c = threadIdx.x & 63;
  float a = 0.f;
  const float* ip = istyle + b * 512;
  const float* wp = sw + c * 512;
  for (int l = 0; l < 512; ++l) a += ip[l] * wp[l];
  styleb[b * 64 + c] = a + sb[c];
}

// ---------------- pk: Gpart(bf16)[b][ch][256][80] = exp(kw@X) @ [X^T | 1 | 0] ------------
__global__ __launch_bounds__(256, 2) void pk_kernel(const float* __restrict__ nz,
                                                    const short* __restrict__ kwb,
                                                    short* __restrict__ Gpartb) {
  __shared__ __attribute__((aligned(16))) char lds[57600];
  int b = blockIdx.y, ch = blockIdx.x;
  int tid = threadIdx.x;
  int w = tid >> 6, lane = tid & 63, quad = lane >> 4, l15 = lane & 15;
  int n0 = ch * 128;
  short* Xb = (short*)lds;
  short* Xt = (short*)(lds + 21760);
  short* Ph = (short*)(lds + 40192);
  for (int k = 0; k < 32; ++k) {
    int idx = tid + k * 256;
    int c = idx >> 7, n = idx & 127;
    float v = nz[((long)b * 64 + c) * NPIX + n0 + n];
    short bv = f2bf(v);
    Xb[c * 136 + n] = bv;
    Xt[n * 72 + c] = bv;
  }
  for (int k = 0; k < 8; ++k) {
    int idx = tid + k * 256;
    int c = 64 + (idx >> 7), n = idx & 127;
    Xb[c * 136 + n] = (c == 64) ? (short)0x3F80 : (short)0;
  }
  __syncthreads();
  for (int q = 0; q < 4; ++q) {
    f32x4 acc[2][4];
#pragma unroll
    for (int j = 0; j < 2; ++j)
#pragma unroll
      for (int dt = 0; dt < 4; ++dt) acc[j][dt] = (f32x4){0.f, 0.f, 0.f, 0.f};
#pragma unroll
    for (int j = 0; j < 2; ++j) {
      int ntile = 2 * w + j;
#pragma unroll
      for (int ks = 0; ks < 2; ++ks) {
        bf16x8 bfr = *(const bf16x8*)(Xt + (ntile * 16 + l15) * 72 + ks * 32 + quad * 8);
#pragma unroll
        for (int dt = 0; dt < 4; ++dt) {
          bf16x8 afr = *(const bf16x8*)(kwb + ((q * 64 + dt * 16 + l15) * 64 + ks * 32 + quad * 8));
          acc[j][dt] = MFMA16(afr, bfr, acc[j][dt]);
        }
      }
    }
#pragma unroll
    for (int j = 0; j < 2; ++j) {
      int ntile = 2 * w + j;
#pragma unroll
      for (int dt = 0; dt < 4; ++dt)
#pragma unroll
        for (int r = 0; r < 4; ++r) {
          float p = __expf(acc[j][dt][r] * QKSCALE);
          Ph[(dt * 16 + quad * 4 + r) * 136 + ntile * 16 + l15] = f2bf(p);
        }
    }
    __syncthreads();
#pragma unroll
    for (int ct = 0; ct < 5; ++ct) {
      f32x4 g = (f32x4){0.f, 0.f, 0.f, 0.f};
#pragma unroll
      for (int ks = 0; ks < 4; ++ks) {
        bf16x8 afr = *(const bf16x8*)(Ph + (w * 16 + l15) * 136 + ks * 32 + quad * 8);
        bf16x8 bfr = *(const bf16x8*)(Xb + (ct * 16 + l15) * 136 + ks * 32 + quad * 8);
        g = MFMA16(afr, bfr, g);
      }
#pragma unroll
      for (int r = 0; r < 4; ++r) {
        int row = q * 64 + w * 16 + quad * 4 + r;
        Gpartb[(((long)b * 128 + ch) * 256 + row) * 80 + ct * 16 + l15] = f2bf(g[r]);
      }
    }
    __syncthreads();
  }
}

// ---------------- ctxM: merge Gpart(bf16) -> ctx -> MtT (bf16 [b][64c][256d]) ------------
__global__ void ctxM_kernel(const short* __restrict__ Gpartb, const float* __restrict__ vw,
                            const float* __restrict__ ow, short* __restrict__ MtTb) {
  int b = blockIdx.y, dt = blockIdx.x * 16;
  int h = dt >> 5;
  __shared__ float Gs[16][81];
  __shared__ float ctxs[16][68];
  int t = threadIdx.x;
  for (int idx = t; idx < 1280; idx += 256) {
    int dl = idx / 80, c = idx - dl * 80;
    float s = 0.f;
    const short* gp = Gpartb + ((long)b * 128 * 256 + (dt + dl)) * 80 + c;
    for (int ch = 0; ch < 128; ++ch) s += bf2f(gp[(long)ch * 20480]);
    Gs[dl][c] = s;
  }
  __syncthreads();
  for (int idx = t; idx < 1024; idx += 256) {
    int dl = idx & 15, e = idx >> 4;
    const float* vp = vw + (h * 64 + e) * 64;
    float a = 0.f;
#pragma unroll
    for (int c = 0; c < 64; ++c) a += Gs[dl][c] * vp[c];
    ctxs[dl][e] = a / Gs[dl][64];
  }
  __syncthreads();
  for (int idx = t; idx < 1024; idx += 256) {
    int dl = idx & 15, c = idx >> 4;
    const float* op = ow + c * 512 + h * 64;
    float a = 0.f;
#pragma unroll
    for (int e = 0; e < 64; ++e) a += op[e] * ctxs[dl][e];
    MtTb[((long)b * 64 + c) * 256 + dt + dl] = f2bf(a);
  }
}

// ---------------- fused attn+FF + MFMA 3x3 conv (+optional rgb epilogue) -----------------
// grid (128 y, NB), 4 waves. wave w: x in [32w, 32w+32) as 2 ntiles of 16.
// Phase A: per-ntile attn pipeline (attnd3) -> addv registers.
// Phase B: 9-shift MFMA conv over NHWC bf16 input.
// Epilogue: lrelu(conv + addv) -> NCHW fp32 / NHWC bf16; optional rgb 1x1 + prev.
__global__ __launch_bounds__(256, 3) void convattn_kernel(
    const short* __restrict__ inT, int CI, const short* __restrict__ wb,
    const float* __restrict__ nz, const short* __restrict__ qwb,
    const short* __restrict__ MtTb, const float* __restrict__ ob,
    const float* __restrict__ gap, const short* __restrict__ f1wb,
    const float* __restrict__ f1b, const short* __restrict__ f2wb,
    const float* __restrict__ f2b, const float* __restrict__ gfp,
    float* __restrict__ out_nchw, short* __restrict__ out_nhwc,
    const float* __restrict__ rgbw, const float* __restrict__ styleb,
    const float* __restrict__ prev, float* __restrict__ rgbs) {
  __shared__ __attribute__((aligned(16))) char lds[43008];
  int b = blockIdx.y, y = blockIdx.x;
  int tid = threadIdx.x;
  int w = tid >> 6, lane = tid & 63, quad = lane >> 4, l15 = lane & 15;
  float ga = gap[0], gf = gfp[0];
  char* wbase = lds + w * 10752;
  short* Xt = (short*)wbase;           // [16n][72c]
  short* Eb = (short*)(wbase + 2304);  // [16n][264d]
  short* Yb = (short*)(wbase + 2304);  // [16n][72c] overlays Eb
  short* Hb = (short*)(wbase + 4608);  // [16n][136j]
  float addv[2][4][4];
  // ---- Phase A: attention+FF for this wave's 32 pixels (2 ntiles) ----
  for (int j = 0; j < 2; ++j) {
    int n0 = y * 128 + (2 * w + j) * 16;
#pragma unroll
    for (int k = 0; k < 16; ++k) {
      int c = quad + 4 * k;
      float v = nz[((long)b * 64 + c) * NPIX + n0 + l15];
      Xt[l15 * 72 + c] = f2bf(v);
    }
    f32x4 acc1[16];
#pragma unroll
    for (int dt = 0; dt < 16; ++dt) acc1[dt] = (f32x4){0.f, 0.f, 0.f, 0.f};
#pragma unroll
    for (int ks = 0; ks < 2; ++ks) {
      bf16x8 bfr = *(const bf16x8*)(Xt + l15 * 72 + ks * 32 + quad * 8);
#pragma unroll
      for (int dt = 0; dt < 16; ++dt) {
        bf16x8 afr = *(const bf16x8*)(qwb + ((dt * 16 + l15) * 64 + ks * 32 + quad * 8));
        acc1[dt] = MFMA16(afr, bfr, acc1[dt]);
      }
    }
#pragma unroll
    for (int h = 0; h < 8; ++h) {
      float part = 0.f;
#pragma unroll
      for (int dd = 0; dd < 2; ++dd) {
        int dt = 2 * h + dd;
#pragma unroll
        for (int r = 0; r < 4; ++r) {
          float e = __expf(acc1[dt][r] * QKSCALE);
          acc1[dt][r] = e;
          part += e;
        }
      }
      float p2 = part + __shfl_xor(part, 16);
      float s = p2 + __shfl_xor(p2, 32);
      float inv = 1.0f / s;
#pragma unroll
      for (int dd = 0; dd < 2; ++dd) {
        int dt = 2 * h + dd;
#pragma unroll
        for (int r = 0; r < 4; ++r)
          Eb[l15 * 264 + dt * 16 + quad * 4 + r] = f2bf(acc1[dt][r] * inv);
      }
    }
    const short* mtb = MtTb + (long)b * 64 * 256;
    f32x4 acc2[4];
#pragma unroll
    for (int ct = 0; ct < 4; ++ct) acc2[ct] = (f32x4){0.f, 0.f, 0.f, 0.f};
#pragma unroll
    for (int ks = 0; ks < 8; ++ks) {
      bf16x8 bfr = *(const bf16x8*)(Eb + l15 * 264 + ks * 32 + quad * 8);
#pragma unroll
      for (int ct = 0; ct < 4; ++ct) {
        bf16x8 afr = *(const bf16x8*)(mtb + ((ct * 16 + l15) * 256 + ks * 32 + quad * 8));
        acc2[ct] = MFMA16(afr, bfr, acc2[ct]);
      }
    }
    float yreg[4][4];
#pragma unroll
    for (int ct = 0; ct < 4; ++ct)
#pragma unroll
      for (int r = 0; r < 4; ++r) {
        int c = ct * 16 + quad * 4 + r;
        float xv = nz[((long)b * 64 + c) * NPIX + n0 + l15];
        float yv = xv + ga * (acc2[ct][r] + ob[c]);
        yreg[ct][r] = yv;
        Yb[l15 * 72 + c] = f2bf(yv);
      }
    f32x4 acc3[8];
#pragma unroll
    for (int jt = 0; jt < 8; ++jt) acc3[jt] = (f32x4){0.f, 0.f, 0.f, 0.f};
#pragma unroll
    for (int ks = 0; ks < 2; ++ks) {
      bf16x8 bfr = *(const bf16x8*)(Yb + l15 * 72 + ks * 32 + quad * 8);
#pragma unroll
      for (int jt = 0; jt < 8; ++jt) {
        bf16x8 afr = *(const bf16x8*)(f1wb + ((jt * 16 + l15) * 64 + ks * 32 + quad * 8));
        acc3[jt] = MFMA16(afr, bfr, acc3[jt]);
      }
    }
#pragma unroll
    for (int jt = 0; jt < 8; ++jt)
#pragma unroll
      for (int r = 0; r < 4; ++r) {
        int jj = jt * 16 + quad * 4 + r;
        float a = acc3[jt][r] + f1b[jj];
        a = a > 0.f ? a : 0.2f * a;
        Hb[l15 * 136 + jj] = f2bf(a);
      }
    f32x4 acc4[4];
#pragma unroll
    for (int ct = 0; ct < 4; ++ct) acc4[ct] = (f32x4){0.f, 0.f, 0.f, 0.f};
#pragma unroll
    for (int ks = 0; ks < 4; ++ks) {
      bf16x8 bfr = *(const bf16x8*)(Hb + l15 * 136 + ks * 32 + quad * 8);
#pragma unroll
      for (int ct = 0; ct < 4; ++ct) {
        bf16x8 afr = *(const bf16x8*)(f2wb + ((ct * 16 + l15) * 128 + ks * 32 + quad * 8));
        acc4[ct] = MFMA16(afr, bfr, acc4[ct]);
      }
    }
#pragma unroll
    for (int ct = 0; ct < 4; ++ct)
#pragma unroll
      for (int r = 0; r < 4; ++r) {
        int c = ct * 16 + quad * 4 + r;
        addv[j][ct][r] = yreg[ct][r] + gf * (acc4[ct][r] + f2b[c]);
      }
  }
  __syncthreads();   // attn strips dead; Bs reuses lds
  // ---- Phase B: 3x3 conv via 9 shift-GEMMs ----
  short* Bs = (short*)lds;   // [3r][130xi][40 ci-pad]
  int KS = CI >> 5;
  f32x4 acc[2][4];
#pragma unroll
  for (int j = 0; j < 2; ++j)
#pragma unroll
    for (int ct = 0; ct < 4; ++ct) acc[j][ct] = (f32x4){0.f, 0.f, 0.f, 0.f};
  for (int ks = 0; ks < KS; ++ks) {
    if (ks) __syncthreads();
    for (int t = tid; t < 1560; t += 256) {
      int ci8 = t & 3, xr = t >> 2;
      int xi = xr % 130, r = xr / 130;
      int gy = y + r - 1, gx = xi - 1;
      bf16x8 v = {0, 0, 0, 0, 0, 0, 0, 0};
      if (gy >= 0 && gy < 128 && gx >= 0 && gx < 128)
        v = *(const bf16x8*)(inT + (((long)(b * 128 + gy)) * 128 + gx) * CI + ks * 32 + ci8 * 8);
      *(bf16x8*)(Bs + (r * 130 + xi) * 40 + ci8 * 8) = v;
    }
    __syncthreads();
#pragma unroll
    for (int sh = 0; sh < 9; ++sh) {
      int dyv = sh / 3, dxv = sh - dyv * 3;
      const short* wrow = wb + (sh * 64 + l15) * CI + ks * 32 + quad * 8;
      bf16x8 a0 = *(const bf16x8*)(wrow);
      bf16x8 a1 = *(const bf16x8*)(wrow + 16 * CI);
      bf16x8 a2 = *(const bf16x8*)(wrow + 32 * CI);
      bf16x8 a3 = *(const bf16x8*)(wrow + 48 * CI);
#pragma unroll
      for (int j = 0; j < 2; ++j) {
        int xi = (2 * w + j) * 16 + l15 + dxv;
        bf16x8 bf = *(const bf16x8*)(Bs + (dyv * 130 + xi) * 40 + quad * 8);
        acc[j][0] = MFMA16(a0, bf, acc[j][0]);
        acc[j][1] = MFMA16(a1, bf, acc[j][1]);
        acc[j][2] = MFMA16(a2, bf, acc[j][2]);
        acc[j][3] = MFMA16(a3, bf, acc[j][3]);
      }
    }
  }
  // ---- Epilogue: lrelu(conv + attn), stores, optional rgb ----
#pragma unroll
  for (int j = 0; j < 2; ++j) {
    int x = (2 * w + j) * 16 + l15;
    float p0 = 0.f, p1 = 0.f, p2 = 0.f;
#pragma unroll
    for (int ct = 0; ct < 4; ++ct) {
      float v[4];
#pragma unroll
      for (int r = 0; r < 4; ++r) {
        float a = acc[j][ct][r] + addv[j][ct][r];
        v[r] = a > 0.f ? a : 0.2f * a;
      }
      if (out_nchw) {
#pragma unroll
        for (int r = 0; r < 4; ++r) {
          int co = ct * 16 + quad * 4 + r;
          out_nchw[((long)(b * 64 + co)) * 16384 + y * 128 + x] = v[r];
        }
      }
      if (out_nhwc) {
        short4 pv;
        pv.x = f2bf(v[0]); pv.y = f2bf(v[1]); pv.z = f2bf(v[2]); pv.w = f2bf(v[3]);
        *(short4*)(out_nhwc + (((long)(b * 128 + y)) * 128 + x) * 64 + ct * 16 + quad * 4) = pv;
      }
      if (rgbw) {
#pragma unroll
        for (int r = 0; r < 4; ++r) {
          int co = ct * 16 + quad * 4 + r;
          float mv = (styleb[b * 64 + co] + 1.0f) * v[r];
          p0 += rgbw[co] * mv;
          p1 += rgbw[64 + co] * mv;
          p2 += rgbw[128 + co] * mv;
        }
      }
    }
    if (rgbw) {
      p0 += __shfl_xor(p0, 16); p0 += __shfl_xor(p0, 32);
      p1 += __shfl_xor(p1, 16); p1 += __shfl_xor(p1, 32);
      p2 += __shfl_xor(p2, 16); p2 += __shfl_xor(p2, 32);
      if (quad == 0) {
        long pi = y * 128 + x;
        rgbs[((long)(b * 3 + 0)) * 16384 + pi] = p0 + prev[((long)(b * 3 + 0)) * 16384 + pi];
        rgbs[((long)(b * 3 + 1)) * 16384 + pi] = p1 + prev[((long)(b * 3 + 1)) * 16384 + pi];
        rgbs[((long)(b * 3 + 2)) * 16384 + pi] = p2 + prev[((long)(b * 3 + 2)) * 16384 + pi];
      }
    }
  }
}

// ---------------- fused bilinear up2 + [1,2,1] blur (rgb tail) ---------------------------
// grid (256 Y, 12 bc), 256 threads (one out px each)
__global__ void upblur_kernel(const float* __restrict__ rgbs, float* __restrict__ out) {
  __shared__ float rows[3][128];
  int bc = blockIdx.y, Y = blockIdx.x, X = threadIdx.x;
  int m = Y >> 1;
  const float* base = rgbs + (long)bc * 16384;
  for (int t = X; t < 384; t += 256) {
    int sr = t >> 7, xx = t & 127;
    int rr = m - 1 + sr;
    rr = rr < 0 ? 0 : (rr > 127 ? 127 : rr);
    rows[sr][xx] = base[rr * 128 + xx];
  }
  __syncthreads();
  const float w3[3] = {1.f, 2.f, 1.f};
  float s = 0.f;
#pragma unroll
  for (int dy = -1; dy <= 1; ++dy) {
    int Yv = Y + dy;
    if (Yv < 0 || Yv > 255) continue;
    float iy = Yv * 0.5f - 0.25f;
    int y0 = (int)floorf(iy); float wy = iy - (float)y0;
    int ylo = y0 < 0 ? 0 : y0;
    int yhi = y0 + 1 > 127 ? 127 : y0 + 1;
    int slo = ylo - m + 1, shi = yhi - m + 1;
#pragma unroll
    for (int dx = -1; dx <= 1; ++dx) {
      int Xv = X + dx;
      if (Xv < 0 || Xv > 255) continue;
      float ix = Xv * 0.5f - 0.25f;
      int x0 = (int)floorf(ix); float wx = ix - (float)x0;
      int xlo = x0 < 0 ? 0 : x0;
      int xhi = x0 + 1 > 127 ? 127 : x0 + 1;
      float v = (1.f - wy) * ((1.f - wx) * rows[slo][xlo] + wx * rows[slo][xhi])
              + wy * ((1.f - wx) * rows[shi][xlo] + wx * rows[shi][xhi]);
      s += w3[dy + 1] * w3[dx + 1] * v;
    }
  }
  out[(long)bc * 65536 + Y * 256 + X] = s * (1.0f / 16.0f);
}

extern "C" void kernel_launch(void* const* d_in, const int* in_sizes, int n_in,
                              void* d_out, int out_size, void* d_ws, size_t ws_size,
                              hipStream_t stream) {
  (void)in_sizes; (void)n_in; (void)out_size; (void)ws_size;
  const float* x        = (const float*)d_in[0];
  const float* prev_rgb = (const float*)d_in[1];
  const float* istyle   = (const float*)d_in[2];
  const float* noise1   = (const float*)d_in[3];
  const float* noise2   = (const float*)d_in[4];
  const float* conv1_w  = (const float*)d_in[5];
  const float* conv2_w  = (const float*)d_in[6];
  const float* style_w  = (const float*)d_in[7];
  const float* style_b  = (const float*)d_in[8];
  const float* rgb_w    = (const float*)d_in[9];
  const float* qw       = (const float*)d_in[10];
  const float* kw       = (const float*)d_in[11];
  const float* vw       = (const float*)d_in[12];
  const float* ow       = (const float*)d_in[13];
  const float* ob       = (const float*)d_in[14];
  const float* ga       = (const float*)d_in[15];
  const float* f1w      = (const float*)d_in[16];
  const float* f1b      = (const float*)d_in[17];
  const float* f2w      = (const float*)d_in[18];
  const float* f2b      = (const float*)d_in[19];
  const float* gf       = (const float*)d_in[20];
  float* out_x   = (float*)d_out;
  float* out_rgb = out_x + 4194304;
  float* ws = (float*)d_ws;

  short* xupT   = (short*)(ws + OFF_XUPT);
  short* xaT    = (short*)(ws + OFF_XAT);
  short* Gpartb = (short*)(ws + OFF_GPART);
  short* wb1    = (short*)(ws + OFF_WB1);
  short* wb2    = (short*)(ws + OFF_WB2);
  float* styleb = ws + OFF_STYLE;
  float* rgbs   = ws + OFF_RGBS;
  short* qwb    = (short*)(ws + OFF_QWB);
  short* kwb    = (short*)(ws + OFF_KWB);
  short* f1wb   = (short*)(ws + OFF_F1WB);
  short* f2wb   = (short*)(ws + OFF_F2WB);
  short* MtTb   = (short*)(ws + OFF_MTT);

  // prep
  cvt4_kernel<<<384, 256, 0, stream>>>(qw, kw, f1w, f2w, qwb, kwb, f1wb, f2wb);
  wnormT_kernel<<<64, 256, 0, stream>>>(conv1_w, wb1, 128);
  wnormT_kernel<<<64, 256, 0, stream>>>(conv2_w, wb2, 64);
  style_kernel<<<1, 256, 0, stream>>>(istyle, style_w, style_b, styleb);
  up2t_kernel<<<dim3(128, NB), 256, 0, stream>>>(x, xupT);

  for (int i = 0; i < 2; ++i) {
    const float* nz     = (i == 0) ? noise1 : noise2;
    const short* qwb_i  = qwb + i * DK * NF;
    const short* kwb_i  = kwb + i * DK * NF;
    const float* vw_i   = vw + i * DV * NF;
    const float* ow_i   = ow + i * NF * DV;
    const float* ob_i   = ob + i * NF;
    const short* f1wb_i = f1wb + i * 128 * 64;
    const float* f1b_i  = f1b + i * 128;
    const short* f2wb_i = f2wb + i * 64 * 128;
    const float* f2b_i  = f2b + i * NF;
    pk_kernel<<<dim3(128, NB), 256, 0, stream>>>(nz, kwb_i, Gpartb);
    ctxM_kernel<<<dim3(16, NB), 256, 0, stream>>>(Gpartb, vw_i, ow_i, MtTb);
    if (i == 0) {
      convattn_kernel<<<dim3(128, NB), 256, 0, stream>>>(
          xupT, 128, wb1, nz, qwb_i, MtTb, ob_i, ga + i, f1wb_i, f1b_i, f2wb_i, f2b_i, gf + i,
          nullptr, xaT, nullptr, nullptr, nullptr, nullptr);
    } else {
      convattn_kernel<<<dim3(128, NB), 256, 0, stream>>>(
          xaT, 64, wb2, nz, qwb_i, MtTb, ob_i, ga + i, f1wb_i, f1b_i, f2wb_i, f2b_i, gf + i,
          out_x, nullptr, rgb_w, styleb, prev_rgb, rgbs);
    }
  }

  upblur_kernel<<<dim3(256, 12), 256, 0, stream>>>(rgbs, out_rgb);
}

// Round 6
// 440.092 us; speedup vs baseline: 1.6507x; 1.6507x over previous
//
#include <hip/hip_runtime.h>
#include <math.h>

#define NB 4
#define NF 64
#define NPIX 16384
#define DK 256
#define DV 512
#define QKSCALE 0.4204482f

typedef __attribute__((ext_vector_type(8))) short bf16x8;
typedef __attribute__((ext_vector_type(4))) float f32x4;
#define MFMA16(a, b, c) __builtin_amdgcn_mfma_f32_16x16x32_bf16(a, b, c, 0, 0, 0)

__device__ __forceinline__ short f2bf(float f) {
  unsigned u = __builtin_bit_cast(unsigned, f);
  unsigned r = (u + 0x7FFFu + ((u >> 16) & 1u)) >> 16;
  return (short)r;
}
__device__ __forceinline__ float bf2f(short s) {
  unsigned u = ((unsigned)(unsigned short)s) << 16;
  return __builtin_bit_cast(float, u);
}

// workspace offsets (float units)
#define OFF_XUPT   0L          // bf16 [4][128y][128x][128c]  4,194,304 f
#define OFF_XAT    4194304L    // bf16 [4][128y][128x][64c]   2,097,152 f
#define OFF_NBT    6291456L    // bf16 [4][16384n][64c]       2,097,152 f
#define OFF_GPART  8388608L    // bf16 [4][128][256][80]      5,242,880 f
#define OFF_WB1    13631488L   // bf16 [9][64][128]              36,864 f
#define OFF_WB2    13668352L   // bf16 [9][64][64]               18,432 f
#define OFF_STYLE  13686784L   // [4][64] fp32                      256
#define OFF_RGBS   13687040L   // [4][3][128][128] fp32         196,608
#define OFF_QWB    13883648L   // bf16 [2][256][64]              16,384 f
#define OFF_KWB    13900032L   // bf16 [2][256][64]              16,384 f
#define OFF_F1WB   13916416L   // bf16 [2][128][64]               8,192 f
#define OFF_F2WB   13924608L   // bf16 [2][64][128]               8,192 f
#define OFF_MTT    13932800L   // bf16 [4][64][256]              32,768 f
// total 13,965,568 floats = 55.9 MB

#define CDIV(a,b) (((a)+(b)-1)/(b))

// ---------------- fp32->bf16 for the 4 attn weight tensors in one launch -----------------
__global__ void cvt4_kernel(const float* __restrict__ qw, const float* __restrict__ kw,
                            const float* __restrict__ f1w, const float* __restrict__ f2w,
                            short* __restrict__ qwb, short* __restrict__ kwb,
                            short* __restrict__ f1wb, short* __restrict__ f2wb) {
  int i = blockIdx.x * 256 + threadIdx.x;   // 98304 total
  if (i < 32768) qwb[i] = f2bf(qw[i]);
  else if (i < 65536) kwb[i - 32768] = f2bf(kw[i - 32768]);
  else if (i < 81920) f1wb[i - 65536] = f2bf(f1w[i - 65536]);
  else f2wb[i - 81920] = f2bf(f2w[i - 81920]);
}

// ---------------- fused bilinear up2 + NCHW->NHWC bf16 (x path) --------------------------
__global__ __launch_bounds__(256) void up2t_kernel(const float* __restrict__ in,
                                                   short* __restrict__ outT) {
  __shared__ float row[64 * 132];   // [xin][c] y-interpolated row
  int b = blockIdx.y, y = blockIdx.x, tid = threadIdx.x;
  float iy = y * 0.5f - 0.25f;
  int y0 = (int)floorf(iy); float wy = iy - (float)y0;
  int ylo = y0 < 0 ? 0 : y0;
  int yhi = y0 + 1 > 63 ? 63 : y0 + 1;
  for (int it = 0; it < 32; ++it) {
    int idx = it * 256 + tid;
    int c = idx >> 6, xin = idx & 63;
    const float* bp = in + ((long)(b * 128 + c)) * 4096;
    float v0 = bp[ylo * 64 + xin];
    float v1 = bp[yhi * 64 + xin];
    row[xin * 132 + c] = (1.f - wy) * v0 + wy * v1;
  }
  __syncthreads();
  int x = tid >> 1, c0 = (tid & 1) * 64;
  float ix = x * 0.5f - 0.25f;
  int x0 = (int)floorf(ix); float wx = ix - (float)x0;
  int xlo = x0 < 0 ? 0 : x0;
  int xhi = x0 + 1 > 63 ? 63 : x0 + 1;
  long obase = (((long)(b * 128 + y)) * 128 + x) * 128 + c0;
#pragma unroll
  for (int i = 0; i < 8; ++i) {
    bf16x8 pack;
#pragma unroll
    for (int r = 0; r < 8; ++r) {
      int c = c0 + i * 8 + r;
      float v = (1.f - wx) * row[xlo * 132 + c] + wx * row[xhi * 132 + c];
      pack[r] = f2bf(v);
    }
    *(bf16x8*)(outT + obase + i * 8) = pack;
  }
}

// ---------------- demod weight prep -> bf16 wb[9][64][CI] --------------------------------
__global__ void wnormT_kernel(const float* __restrict__ W, short* __restrict__ wb, int CI) {
  int co = blockIdx.x;
  int n = CI * 9;
  __shared__ float red[256];
  float s = 0.f;
  for (int idx = threadIdx.x; idx < n; idx += 256) {
    float w2 = 2.0f * W[co * n + idx];
    s += w2 * w2;
  }
  red[threadIdx.x] = s;
  __syncthreads();
  for (int off = 128; off > 0; off >>= 1) {
    if (threadIdx.x < off) red[threadIdx.x] += red[threadIdx.x + off];
    __syncthreads();
  }
  float sc = rsqrtf(red[0] + 1e-8f);
  for (int idx = threadIdx.x; idx < n; idx += 256) {
    int ci = idx / 9, k = idx - ci * 9;
    wb[(k * 64 + co) * CI + ci] = f2bf(2.0f * W[co * n + idx] * sc);
  }
}

// ---------------- style ------------------------------------------------------------------
__global__ void style_kernel(const float* __restrict__ istyle, const float* __restrict__ sw,
                             const float* __restrict__ sb, float* __restrict__ styleb) {
  int b = threadIdx.x >> 6;
  int c = threadIdx.x & 63;
  float a = 0.f;
  const float* ip = istyle + b * 512;
  const float* wp = sw + c * 512;
  for (int l = 0; l < 512; ++l) a += ip[l] * wp[l];
  styleb[b * 64 + c] = a + sb[c];
}

// ---------------- pk: Gpart(bf16)[b][ch][256][80] = exp(kw@X) @ [X^T | 1 | 0] ------------
__global__ __launch_bounds__(256, 2) void pk_kernel(const float* __restrict__ nz,
                                                    const short* __restrict__ kwb,
                                                    short* __restrict__ Gpartb) {
  __shared__ __attribute__((aligned(16))) char lds[57600];
  int b = blockIdx.y, ch = blockIdx.x;
  int tid = threadIdx.x;
  int w = tid >> 6, lane = tid & 63, quad = lane >> 4, l15 = lane & 15;
  int n0 = ch * 128;
  short* Xb = (short*)lds;
  short* Xt = (short*)(lds + 21760);
  short* Ph = (short*)(lds + 40192);
  for (int k = 0; k < 32; ++k) {
    int idx = tid + k * 256;
    int c = idx >> 7, n = idx & 127;
    float v = nz[((long)b * 64 + c) * NPIX + n0 + n];
    short bv = f2bf(v);
    Xb[c * 136 + n] = bv;
    Xt[n * 72 + c] = bv;
  }
  for (int k = 0; k < 8; ++k) {
    int idx = tid + k * 256;
    int c = 64 + (idx >> 7), n = idx & 127;
    Xb[c * 136 + n] = (c == 64) ? (short)0x3F80 : (short)0;
  }
  __syncthreads();
  for (int q = 0; q < 4; ++q) {
    f32x4 acc[2][4];
#pragma unroll
    for (int j = 0; j < 2; ++j)
#pragma unroll
      for (int dt = 0; dt < 4; ++dt) acc[j][dt] = (f32x4){0.f, 0.f, 0.f, 0.f};
#pragma unroll
    for (int j = 0; j < 2; ++j) {
      int ntile = 2 * w + j;
#pragma unroll
      for (int ks = 0; ks < 2; ++ks) {
        bf16x8 bfr = *(const bf16x8*)(Xt + (ntile * 16 + l15) * 72 + ks * 32 + quad * 8);
#pragma unroll
        for (int dt = 0; dt < 4; ++dt) {
          bf16x8 afr = *(const bf16x8*)(kwb + ((q * 64 + dt * 16 + l15) * 64 + ks * 32 + quad * 8));
          acc[j][dt] = MFMA16(afr, bfr, acc[j][dt]);
        }
      }
    }
#pragma unroll
    for (int j = 0; j < 2; ++j) {
      int ntile = 2 * w + j;
#pragma unroll
      for (int dt = 0; dt < 4; ++dt)
#pragma unroll
        for (int r = 0; r < 4; ++r) {
          float p = __expf(acc[j][dt][r] * QKSCALE);
          Ph[(dt * 16 + quad * 4 + r) * 136 + ntile * 16 + l15] = f2bf(p);
        }
    }
    __syncthreads();
#pragma unroll
    for (int ct = 0; ct < 5; ++ct) {
      f32x4 g = (f32x4){0.f, 0.f, 0.f, 0.f};
#pragma unroll
      for (int ks = 0; ks < 4; ++ks) {
        bf16x8 afr = *(const bf16x8*)(Ph + (w * 16 + l15) * 136 + ks * 32 + quad * 8);
        bf16x8 bfr = *(const bf16x8*)(Xb + (ct * 16 + l15) * 136 + ks * 32 + quad * 8);
        g = MFMA16(afr, bfr, g);
      }
#pragma unroll
      for (int r = 0; r < 4; ++r) {
        int row = q * 64 + w * 16 + quad * 4 + r;
        Gpartb[(((long)b * 128 + ch) * 256 + row) * 80 + ct * 16 + l15] = f2bf(g[r]);
      }
    }
    __syncthreads();
  }
}

// ---------------- ctxM: merge Gpart(bf16) -> ctx -> MtT (bf16 [b][64c][256d]) ------------
__global__ void ctxM_kernel(const short* __restrict__ Gpartb, const float* __restrict__ vw,
                            const float* __restrict__ ow, short* __restrict__ MtTb) {
  int b = blockIdx.y, dt = blockIdx.x * 16;
  int h = dt >> 5;
  __shared__ float Gs[16][81];
  __shared__ float ctxs[16][68];
  int t = threadIdx.x;
  for (int idx = t; idx < 1280; idx += 256) {
    int dl = idx / 80, c = idx - dl * 80;
    float s = 0.f;
    const short* gp = Gpartb + ((long)b * 128 * 256 + (dt + dl)) * 80 + c;
    for (int ch = 0; ch < 128; ++ch) s += bf2f(gp[(long)ch * 20480]);
    Gs[dl][c] = s;
  }
  __syncthreads();
  for (int idx = t; idx < 1024; idx += 256) {
    int dl = idx & 15, e = idx >> 4;
    const float* vp = vw + (h * 64 + e) * 64;
    float a = 0.f;
#pragma unroll
    for (int c = 0; c < 64; ++c) a += Gs[dl][c] * vp[c];
    ctxs[dl][e] = a / Gs[dl][64];
  }
  __syncthreads();
  for (int idx = t; idx < 1024; idx += 256) {
    int dl = idx & 15, c = idx >> 4;
    const float* op = ow + c * 512 + h * 64;
    float a = 0.f;
#pragma unroll
    for (int e = 0; e < 64; ++e) a += op[e] * ctxs[dl][e];
    MtTb[((long)b * 64 + c) * 256 + dt + dl] = f2bf(a);
  }
}

// ---------------- attnd4: per-head fused attn+FF, low-LDS, NHWC bf16 out -----------------
// grid (256, NB), block 256 = 4 waves, 16 px/wave. Per-wave LDS 4096 B:
//   Xt [16][72] (X -> Y -> H-chunk) @+0 ; Es [16][56] @+1152 shorts
__global__ __launch_bounds__(256, 5) void attnd4_kernel(
    const float* __restrict__ nz, const short* __restrict__ qwb,
    const short* __restrict__ MtTb, const float* __restrict__ ob,
    const float* __restrict__ gap, const short* __restrict__ f1wb,
    const float* __restrict__ f1b, const short* __restrict__ f2wb,
    const float* __restrict__ f2b, const float* __restrict__ gfp,
    short* __restrict__ noutT) {
  __shared__ __attribute__((aligned(16))) short lds[4 * 2048];
  int b = blockIdx.y;
  int tid = threadIdx.x;
  int w = tid >> 6, lane = tid & 63, quad = lane >> 4, l15 = lane & 15;
  int n0 = blockIdx.x * 64 + w * 16;
  short* Xt = lds + w * 2048;     // [16][72]
  short* Es = Xt + 1152;          // [16][56]
  float ga = gap[0], gf = gfp[0];
  // stage X (bf16)
#pragma unroll
  for (int k = 0; k < 16; ++k) {
    int c = quad + 4 * k;
    Xt[l15 * 72 + c] = f2bf(nz[((long)b * 64 + c) * NPIX + n0 + l15]);
  }
  bf16x8 xfr0 = *(const bf16x8*)(Xt + l15 * 72 + quad * 8);
  bf16x8 xfr1 = *(const bf16x8*)(Xt + l15 * 72 + 32 + quad * 8);
  const short* mtb = MtTb + (long)b * 64 * 256;
  f32x4 acc2[4];
#pragma unroll
  for (int ct = 0; ct < 4; ++ct) acc2[ct] = (f32x4){0.f, 0.f, 0.f, 0.f};
  // per-head: GEMM1 (q) -> softmax -> E-strip -> GEMM2 chunk
#pragma unroll
  for (int h = 0; h < 8; ++h) {
    f32x4 q[2];
#pragma unroll
    for (int dd = 0; dd < 2; ++dd) {
      q[dd] = (f32x4){0.f, 0.f, 0.f, 0.f};
      bf16x8 a0 = *(const bf16x8*)(qwb + (((2 * h + dd) * 16 + l15) * 64 + quad * 8));
      q[dd] = MFMA16(a0, xfr0, q[dd]);
      bf16x8 a1 = *(const bf16x8*)(qwb + (((2 * h + dd) * 16 + l15) * 64 + 32 + quad * 8));
      q[dd] = MFMA16(a1, xfr1, q[dd]);
    }
    float part = 0.f;
#pragma unroll
    for (int dd = 0; dd < 2; ++dd)
#pragma unroll
      for (int r = 0; r < 4; ++r) {
        float e = __expf(q[dd][r] * QKSCALE);
        q[dd][r] = e;
        part += e;
      }
    float p2 = part + __shfl_xor(part, 16);
    float s = p2 + __shfl_xor(p2, 32);
    float inv = 1.0f / s;
#pragma unroll
    for (int dd = 0; dd < 2; ++dd) {
      short4 ev;
      ev.x = f2bf(q[dd][0] * inv); ev.y = f2bf(q[dd][1] * inv);
      ev.z = f2bf(q[dd][2] * inv); ev.w = f2bf(q[dd][3] * inv);
      *(short4*)(Es + l15 * 56 + dd * 16 + quad * 4) = ev;
    }
    bf16x8 efr = *(const bf16x8*)(Es + l15 * 56 + quad * 8);
#pragma unroll
    for (int ct = 0; ct < 4; ++ct) {
      bf16x8 afr = *(const bf16x8*)(mtb + ((ct * 16 + l15) * 256 + h * 32 + quad * 8));
      acc2[ct] = MFMA16(afr, efr, acc2[ct]);
    }
  }
  // residual y = x + ga*(o + ob): x from LDS bf16, y back to Xt + fp32 regs
  float yreg[4][4];
#pragma unroll
  for (int ct = 0; ct < 4; ++ct) {
    int c0 = ct * 16 + quad * 4;
    short4 xs = *(const short4*)(Xt + l15 * 72 + c0);
    float xv[4] = {bf2f(xs.x), bf2f(xs.y), bf2f(xs.z), bf2f(xs.w)};
    short4 ys;
#pragma unroll
    for (int r = 0; r < 4; ++r) yreg[ct][r] = xv[r] + ga * (acc2[ct][r] + ob[c0 + r]);
    ys.x = f2bf(yreg[ct][0]); ys.y = f2bf(yreg[ct][1]);
    ys.z = f2bf(yreg[ct][2]); ys.w = f2bf(yreg[ct][3]);
    *(short4*)(Xt + l15 * 72 + c0) = ys;
  }
  bf16x8 yfr0 = *(const bf16x8*)(Xt + l15 * 72 + quad * 8);
  bf16x8 yfr1 = *(const bf16x8*)(Xt + l15 * 72 + 32 + quad * 8);
  // GEMM3: h1[128j x 16n]
  f32x4 acc3[8];
#pragma unroll
  for (int jt = 0; jt < 8; ++jt) {
    acc3[jt] = (f32x4){0.f, 0.f, 0.f, 0.f};
    bf16x8 a0 = *(const bf16x8*)(f1wb + ((jt * 16 + l15) * 64 + quad * 8));
    acc3[jt] = MFMA16(a0, yfr0, acc3[jt]);
    bf16x8 a1 = *(const bf16x8*)(f1wb + ((jt * 16 + l15) * 64 + 32 + quad * 8));
    acc3[jt] = MFMA16(a1, yfr1, acc3[jt]);
  }
  // GEMM4 in 2 chunks of 64 j through the Xt strip
  f32x4 acc4[4];
#pragma unroll
  for (int ct = 0; ct < 4; ++ct) acc4[ct] = (f32x4){0.f, 0.f, 0.f, 0.f};
#pragma unroll
  for (int p = 0; p < 2; ++p) {
#pragma unroll
    for (int jj = 0; jj < 4; ++jj) {
      int jt = p * 4 + jj;
      short4 hs;
#pragma unroll
      for (int r = 0; r < 4; ++r) {
        float a = acc3[jt][r] + f1b[jt * 16 + quad * 4 + r];
        a = a > 0.f ? a : 0.2f * a;
        ((short*)&hs)[r] = f2bf(a);
      }
      *(short4*)(Xt + l15 * 72 + jj * 16 + quad * 4) = hs;
    }
    bf16x8 h0 = *(const bf16x8*)(Xt + l15 * 72 + quad * 8);
    bf16x8 h1 = *(const bf16x8*)(Xt + l15 * 72 + 32 + quad * 8);
#pragma unroll
    for (int ct = 0; ct < 4; ++ct) {
      bf16x8 a0 = *(const bf16x8*)(f2wb + ((ct * 16 + l15) * 128 + p * 64 + quad * 8));
      acc4[ct] = MFMA16(a0, h0, acc4[ct]);
      bf16x8 a1 = *(const bf16x8*)(f2wb + ((ct * 16 + l15) * 128 + p * 64 + 32 + quad * 8));
      acc4[ct] = MFMA16(a1, h1, acc4[ct]);
    }
  }
  // output NHWC bf16
#pragma unroll
  for (int ct = 0; ct < 4; ++ct) {
    int c0 = ct * 16 + quad * 4;
    short4 ov;
#pragma unroll
    for (int r = 0; r < 4; ++r)
      ((short*)&ov)[r] = f2bf(yreg[ct][r] + gf * (acc4[ct][r] + f2b[c0 + r]));
    *(short4*)(noutT + ((long)b * NPIX + n0 + l15) * 64 + c0) = ov;
  }
}

// ---------------- MFMA 3x3 conv: NHWC bf16 in, bf16 NHWC addend, lrelu, +rgb -------------
// grid (128 y, NB). wave w -> ntiles {2w,2w+1} x all 4 co-tiles.
__global__ __launch_bounds__(256, 4) void convmfma_kernel(
    const short* __restrict__ inT, int CI, const short* __restrict__ wb,
    const short* __restrict__ addnT, float* __restrict__ out_nchw,
    short* __restrict__ out_nhwc, const float* __restrict__ rgbw,
    const float* __restrict__ styleb, const float* __restrict__ prev,
    float* __restrict__ rgbs) {
  __shared__ __attribute__((aligned(16))) short Bs[3 * 130 * 40];  // [r][xi][ci32 pad40]
  int b = blockIdx.y, y = blockIdx.x;
  int tid = threadIdx.x;
  int w = tid >> 6, lane = tid & 63, quad = lane >> 4, l15 = lane & 15;
  int KS = CI >> 5;
  f32x4 acc[2][4];
#pragma unroll
  for (int j = 0; j < 2; ++j)
#pragma unroll
    for (int ct = 0; ct < 4; ++ct) acc[j][ct] = (f32x4){0.f, 0.f, 0.f, 0.f};
  for (int ks = 0; ks < KS; ++ks) {
    if (ks) __syncthreads();
    for (int t = tid; t < 1560; t += 256) {
      int ci8 = t & 3, xr = t >> 2;
      int xi = xr % 130, r = xr / 130;
      int gy = y + r - 1, gx = xi - 1;
      bf16x8 v = {0, 0, 0, 0, 0, 0, 0, 0};
      if (gy >= 0 && gy < 128 && gx >= 0 && gx < 128)
        v = *(const bf16x8*)(inT + (((long)(b * 128 + gy)) * 128 + gx) * CI + ks * 32 + ci8 * 8);
      *(bf16x8*)(Bs + (r * 130 + xi) * 40 + ci8 * 8) = v;
    }
    __syncthreads();
#pragma unroll
    for (int sh = 0; sh < 9; ++sh) {
      int dyv = sh / 3, dxv = sh - dyv * 3;
      const short* wrow = wb + (sh * 64 + l15) * CI + ks * 32 + quad * 8;
      bf16x8 a0 = *(const bf16x8*)(wrow);
      bf16x8 a1 = *(const bf16x8*)(wrow + 16 * CI);
      bf16x8 a2 = *(const bf16x8*)(wrow + 32 * CI);
      bf16x8 a3 = *(const bf16x8*)(wrow + 48 * CI);
#pragma unroll
      for (int j = 0; j < 2; ++j) {
        int xi = (2 * w + j) * 16 + l15 + dxv;
        bf16x8 bf = *(const bf16x8*)(Bs + (dyv * 130 + xi) * 40 + quad * 8);
        acc[j][0] = MFMA16(a0, bf, acc[j][0]);
        acc[j][1] = MFMA16(a1, bf, acc[j][1]);
        acc[j][2] = MFMA16(a2, bf, acc[j][2]);
        acc[j][3] = MFMA16(a3, bf, acc[j][3]);
      }
    }
  }
  // epilogue: lrelu(conv + addn(bf16 NHWC)), stores, optional rgb
#pragma unroll
  for (int j = 0; j < 2; ++j) {
    int x = (2 * w + j) * 16 + l15;
    long nidx = ((long)(b * 128 + y)) * 128 + x;
    float p0 = 0.f, p1 = 0.f, p2 = 0.f;
#pragma unroll
    for (int ct = 0; ct < 4; ++ct) {
      short4 ad = *(const short4*)(addnT + nidx * 64 + ct * 16 + quad * 4);
      float av[4] = {bf2f(ad.x), bf2f(ad.y), bf2f(ad.z), bf2f(ad.w)};
      float v[4];
#pragma unroll
      for (int r = 0; r < 4; ++r) {
        float a = acc[j][ct][r] + av[r];
        v[r] = a > 0.f ? a : 0.2f * a;
      }
      if (out_nchw) {
#pragma unroll
        for (int r = 0; r < 4; ++r) {
          int co = ct * 16 + quad * 4 + r;
          out_nchw[((long)(b * 64 + co)) * 16384 + y * 128 + x] = v[r];
        }
      }
      if (out_nhwc) {
        short4 pv;
        pv.x = f2bf(v[0]); pv.y = f2bf(v[1]); pv.z = f2bf(v[2]); pv.w = f2bf(v[3]);
        *(short4*)(out_nhwc + nidx * 64 + ct * 16 + quad * 4) = pv;
      }
      if (rgbw) {
#pragma unroll
        for (int r = 0; r < 4; ++r) {
          int co = ct * 16 + quad * 4 + r;
          float mv = (styleb[b * 64 + co] + 1.0f) * v[r];
          p0 += rgbw[co] * mv;
          p1 += rgbw[64 + co] * mv;
          p2 += rgbw[128 + co] * mv;
        }
      }
    }
    if (rgbw) {
      p0 += __shfl_xor(p0, 16); p0 += __shfl_xor(p0, 32);
      p1 += __shfl_xor(p1, 16); p1 += __shfl_xor(p1, 32);
      p2 += __shfl_xor(p2, 16); p2 += __shfl_xor(p2, 32);
      if (quad == 0) {
        long pi = y * 128 + x;
        rgbs[((long)(b * 3 + 0)) * 16384 + pi] = p0 + prev[((long)(b * 3 + 0)) * 16384 + pi];
        rgbs[((long)(b * 3 + 1)) * 16384 + pi] = p1 + prev[((long)(b * 3 + 1)) * 16384 + pi];
        rgbs[((long)(b * 3 + 2)) * 16384 + pi] = p2 + prev[((long)(b * 3 + 2)) * 16384 + pi];
      }
    }
  }
}

// ---------------- fused bilinear up2 + [1,2,1] blur (rgb tail) ---------------------------
__global__ void upblur_kernel(const float* __restrict__ rgbs, float* __restrict__ out) {
  __shared__ float rows[3][128];
  int bc = blockIdx.y, Y = blockIdx.x, X = threadIdx.x;
  int m = Y >> 1;
  const float* base = rgbs + (long)bc * 16384;
  for (int t = X; t < 384; t += 256) {
    int sr = t >> 7, xx = t & 127;
    int rr = m - 1 + sr;
    rr = rr < 0 ? 0 : (rr > 127 ? 127 : rr);
    rows[sr][xx] = base[rr * 128 + xx];
  }
  __syncthreads();
  const float w3[3] = {1.f, 2.f, 1.f};
  float s = 0.f;
#pragma unroll
  for (int dy = -1; dy <= 1; ++dy) {
    int Yv = Y + dy;
    if (Yv < 0 || Yv > 255) continue;
    float iy = Yv * 0.5f - 0.25f;
    int y0 = (int)floorf(iy); float wy = iy - (float)y0;
    int ylo = y0 < 0 ? 0 : y0;
    int yhi = y0 + 1 > 127 ? 127 : y0 + 1;
    int slo = ylo - m + 1, shi = yhi - m + 1;
#pragma unroll
    for (int dx = -1; dx <= 1; ++dx) {
      int Xv = X + dx;
      if (Xv < 0 || Xv > 255) continue;
      float ix = Xv * 0.5f - 0.25f;
      int x0 = (int)floorf(ix); float wx = ix - (float)x0;
      int xlo = x0 < 0 ? 0 : x0;
      int xhi = x0 + 1 > 127 ? 127 : x0 + 1;
      float v = (1.f - wy) * ((1.f - wx) * rows[slo][xlo] + wx * rows[slo][xhi])
              + wy * ((1.f - wx) * rows[shi][xlo] + wx * rows[shi][xhi]);
      s += w3[dy + 1] * w3[dx + 1] * v;
    }
  }
  out[(long)bc * 65536 + Y * 256 + X] = s * (1.0f / 16.0f);
}

extern "C" void kernel_launch(void* const* d_in, const int* in_sizes, int n_in,
                              void* d_out, int out_size, void* d_ws, size_t ws_size,
                              hipStream_t stream) {
  (void)in_sizes; (void)n_in; (void)out_size; (void)ws_size;
  const float* x        = (const float*)d_in[0];
  const float* prev_rgb = (const float*)d_in[1];
  const float* istyle   = (const float*)d_in[2];
  const float* noise1   = (const float*)d_in[3];
  const float* noise2   = (const float*)d_in[4];
  const float* conv1_w  = (const float*)d_in[5];
  const float* conv2_w  = (const float*)d_in[6];
  const float* style_w  = (const float*)d_in[7];
  const float* style_b  = (const float*)d_in[8];
  const float* rgb_w    = (const float*)d_in[9];
  const float* qw       = (const float*)d_in[10];
  const float* kw       = (const float*)d_in[11];
  const float* vw       = (const float*)d_in[12];
  const float* ow       = (const float*)d_in[13];
  const float* ob       = (const float*)d_in[14];
  const float* ga       = (const float*)d_in[15];
  const float* f1w      = (const float*)d_in[16];
  const float* f1b      = (const float*)d_in[17];
  const float* f2w      = (const float*)d_in[18];
  const float* f2b      = (const float*)d_in[19];
  const float* gf       = (const float*)d_in[20];
  float* out_x   = (float*)d_out;
  float* out_rgb = out_x + 4194304;
  float* ws = (float*)d_ws;

  short* xupT   = (short*)(ws + OFF_XUPT);
  short* xaT    = (short*)(ws + OFF_XAT);
  short* nbufT  = (short*)(ws + OFF_NBT);
  short* Gpartb = (short*)(ws + OFF_GPART);
  short* wb1    = (short*)(ws + OFF_WB1);
  short* wb2    = (short*)(ws + OFF_WB2);
  float* styleb = ws + OFF_STYLE;
  float* rgbs   = ws + OFF_RGBS;
  short* qwb    = (short*)(ws + OFF_QWB);
  short* kwb    = (short*)(ws + OFF_KWB);
  short* f1wb   = (short*)(ws + OFF_F1WB);
  short* f2wb   = (short*)(ws + OFF_F2WB);
  short* MtTb   = (short*)(ws + OFF_MTT);

  // prep
  cvt4_kernel<<<384, 256, 0, stream>>>(qw, kw, f1w, f2w, qwb, kwb, f1wb, f2wb);
  wnormT_kernel<<<64, 256, 0, stream>>>(conv1_w, wb1, 128);
  wnormT_kernel<<<64, 256, 0, stream>>>(conv2_w, wb2, 64);
  style_kernel<<<1, 256, 0, stream>>>(istyle, style_w, style_b, styleb);
  up2t_kernel<<<dim3(128, NB), 256, 0, stream>>>(x, xupT);

  for (int i = 0; i < 2; ++i) {
    const float* nz     = (i == 0) ? noise1 : noise2;
    const short* qwb_i  = qwb + i * DK * NF;
    const short* kwb_i  = kwb + i * DK * NF;
    const float* vw_i   = vw + i * DV * NF;
    const float* ow_i   = ow + i * NF * DV;
    const float* ob_i   = ob + i * NF;
    const short* f1wb_i = f1wb + i * 128 * 64;
    const float* f1b_i  = f1b + i * 128;
    const short* f2wb_i = f2wb + i * 64 * 128;
    const float* f2b_i  = f2b + i * NF;
    pk_kernel<<<dim3(128, NB), 256, 0, stream>>>(nz, kwb_i, Gpartb);
    ctxM_kernel<<<dim3(16, NB), 256, 0, stream>>>(Gpartb, vw_i, ow_i, MtTb);
    attnd4_kernel<<<dim3(256, NB), 256, 0, stream>>>(nz, qwb_i, MtTb, ob_i, ga + i,
                                                     f1wb_i, f1b_i, f2wb_i, f2b_i, gf + i,
                                                     nbufT);
    if (i == 0) {
      convmfma_kernel<<<dim3(128, NB), 256, 0, stream>>>(
          xupT, 128, wb1, nbufT, nullptr, xaT, nullptr, nullptr, nullptr, nullptr);
    } else {
      convmfma_kernel<<<dim3(128, NB), 256, 0, stream>>>(
          xaT, 64, wb2, nbufT, out_x, nullptr, rgb_w, styleb, prev_rgb, rgbs);
    }
  }

  upblur_kernel<<<dim3(256, 12), 256, 0, stream>>>(rgbs, out_rgb);
}